// Round 7
// baseline (314.644 us; speedup 1.0000x reference)
//
#include <hip/hip_runtime.h>
#include <hip/hip_bf16.h>

typedef __bf16 bf16_t;
typedef __attribute__((ext_vector_type(8))) __bf16 bf16x8;
typedef __attribute__((ext_vector_type(4))) __bf16 bf16x4;
typedef __attribute__((ext_vector_type(4))) float f32x4;

#define E_DIM 256
#define J_DIM 32
#define B_DIM 4096
#define M_DIM (B_DIM * J_DIM)
#define BM 64
#define BK 32
#define LDA 40   // bf16: BK + 8 pad (16B-aligned, spreads banks)
#define LDB 40
#define LDAF 33  // fp32: BK + 1 pad (max 2-way bank alias = free)

#define XK_LDA (E_DIM + 4)  // fp32 xk tile pad: 32-way -> 4-way bank alias

// load 8 consecutive fp32, convert to bf16x8 (RNE)
__device__ inline bf16x8 cvt8(const float* __restrict__ p) {
    f32x4 a = *(const f32x4*)p;
    f32x4 b = *(const f32x4*)(p + 4);
    bf16x8 r;
    r[0] = (bf16_t)a[0]; r[1] = (bf16_t)a[1]; r[2] = (bf16_t)a[2]; r[3] = (bf16_t)a[3];
    r[4] = (bf16_t)b[0]; r[5] = (bf16_t)b[1]; r[6] = (bf16_t)b[2]; r[7] = (bf16_t)b[3];
    return r;
}

// ---------------------------------------------------------------------------
// fused: [0,512): xk[b][j] = <x_b, k_j>  (8 b per block, padded LDS)
//        [512,576): U -> bf16 (RNE, same rounding as in-loop cvt8)
//        [576,608): vkb[j][f] = bias[f] + sum_e V[f,e]*keys[j,e]
// ---------------------------------------------------------------------------
__global__ __launch_bounds__(256) void xkvkb_kernel(
    const float* __restrict__ x, const float* __restrict__ keys,
    const float* __restrict__ U, const float* __restrict__ V,
    const float* __restrict__ bias,
    float* __restrict__ xk, float* __restrict__ vkb, bf16_t* __restrict__ Ubf) {
    __shared__ float smem[(J_DIM + 8) * XK_LDA];   // 40*260 fp32 = 41.6 KB
    int tid = threadIdx.x, bid = blockIdx.x;
    if (bid < 512) {
        float* sK = smem;                          // [32][XK_LDA]
        float* sX = smem + J_DIM * XK_LDA;         // [8][XK_LDA]
        int b0 = bid * 8;
#pragma unroll
        for (int it = 0; it < 8; ++it) {
            int t = it * 256 + tid;
            int r = t >> 6, c = (t & 63) * 4;
            *(f32x4*)(sK + r * XK_LDA + c) = *(const f32x4*)(keys + (size_t)r * E_DIM + c);
        }
#pragma unroll
        for (int it = 0; it < 2; ++it) {
            int t = it * 256 + tid;
            int r = t >> 6, c = (t & 63) * 4;
            *(f32x4*)(sX + r * XK_LDA + c) =
                *(const f32x4*)(x + (size_t)b0 * E_DIM + (size_t)r * E_DIM + c);
        }
        __syncthreads();
        int j = tid & 31, bl = tid >> 5;
        float acc = 0.f;
        for (int e = 0; e < E_DIM; e += 4) {
            f32x4 xv = *(const f32x4*)(sX + bl * XK_LDA + e);
            f32x4 kv = *(const f32x4*)(sK + j * XK_LDA + e);
#pragma unroll
            for (int i = 0; i < 4; ++i) acc += xv[i] * kv[i];
        }
        xk[(size_t)(b0 + bl) * J_DIM + j] = acc;
    } else if (bid < 576) {
        int idx = (bid - 512) * 1024 + tid * 4;
        f32x4 v = *(const f32x4*)(U + idx);
        bf16x4 o;
#pragma unroll
        for (int i = 0; i < 4; ++i) o[i] = (bf16_t)v[i];
        *(bf16x4*)(Ubf + idx) = o;
    } else {
        int j = bid - 576, f = tid;
        float* sk = smem;
        sk[f] = keys[(size_t)j * E_DIM + f];
        __syncthreads();
        float acc = bias[f];
        for (int e = 0; e < E_DIM; e += 4) {
            f32x4 vv = *(const f32x4*)(V + (size_t)f * E_DIM + e);
#pragma unroll
            for (int i = 0; i < 4; ++i) acc += vv[i] * sk[e + i];
        }
        vkb[(size_t)j * E_DIM + f] = acc;
    }
}

// ---------------------------------------------------------------------------
// wx[b][f] = sum_e W[f,e]*x[b,e] — UNCHANGED from round 6 (well-shaped:
// 256 blocks = 64 m-tiles x 4 n-tiles, BM=64 x BN=64).
// ---------------------------------------------------------------------------
__global__ __launch_bounds__(256) void wx_kernel(const float* __restrict__ x,
                                                 const float* __restrict__ W,
                                                 float* __restrict__ wx) {
    __shared__ __align__(16) bf16_t sA[BM][LDA];
    __shared__ __align__(16) bf16_t sBw[64][LDB];
    int tid = threadIdx.x;
    int w = tid >> 6, lane = tid & 63, quad = lane >> 4, l15 = lane & 15;
    int m0 = (blockIdx.x >> 2) * BM, n0 = (blockIdx.x & 3) * 64;
    f32x4 acc[4];
#pragma unroll
    for (int nt = 0; nt < 4; ++nt)
#pragma unroll
        for (int r = 0; r < 4; ++r) acc[nt][r] = 0.f;
    int arow = tid >> 2, akk = (tid & 3) * 8;
    for (int kc = 0; kc < 8; ++kc) {
        int k0 = kc * BK;
        __syncthreads();
        *(bf16x8*)(&sA[arow][akk]) = cvt8(x + (size_t)(m0 + arow) * E_DIM + k0 + akk);
        *(bf16x8*)(&sBw[arow][akk]) = cvt8(W + (size_t)(n0 + arow) * E_DIM + k0 + akk);
        __syncthreads();
        bf16x8 af = *(const bf16x8*)(&sA[w * 16 + l15][quad * 8]);
#pragma unroll
        for (int nt = 0; nt < 4; ++nt) {
            bf16x8 bfr = *(const bf16x8*)(&sBw[nt * 16 + l15][quad * 8]);
            acc[nt] = __builtin_amdgcn_mfma_f32_16x16x32_bf16(af, bfr, acc[nt], 0, 0, 0);
        }
    }
#pragma unroll
    for (int nt = 0; nt < 4; ++nt)
#pragma unroll
        for (int r = 0; r < 4; ++r)
            wx[(size_t)(m0 + w * 16 + quad * 4 + r) * E_DIM + n0 + nt * 16 + l15] =
                acc[nt][r];
}

// ---------------------------------------------------------------------------
// main: round-0 loop with ONE structural change — T14 issue-early/write-late:
//   {issue kc+1 global loads -> regs | compute kc from LDS | barrier |
//    write regs -> LDS | barrier}. Load latency overlaps MFMA+gdot.
// B staged from pre-converted Ubf (r4-validated; halves prefetch regs+bytes).
// Same math, same summation order, same LDS layouts as the 115-us baseline.
// ---------------------------------------------------------------------------
__global__ __launch_bounds__(256) void memcell_kernel(
    const float* __restrict__ x, const float* __restrict__ state,
    const bf16_t* __restrict__ Ubf, const float* __restrict__ wx,
    const float* __restrict__ xk, const float* __restrict__ vkb,
    float* __restrict__ out) {
    __shared__ __align__(16) bf16_t sA[BM][LDA];
    __shared__ __align__(16) bf16_t sB[E_DIM][LDB];
    __shared__ __align__(16) float sAf[BM][LDAF];   // fp32 state tile (gate dot)
    __shared__ __align__(16) float sXf[2][E_DIM];   // fp32 x rows     (gate dot)
    int tid = threadIdx.x;
    int w = tid >> 6, lane = tid & 63, quad = lane >> 4, l15 = lane & 15;
    int m0 = blockIdx.x * BM;
    int b0 = m0 >> 5;                       // block covers b0, b0+1
    f32x4 acc[16];
#pragma unroll
    for (int nt = 0; nt < 16; ++nt)
#pragma unroll
        for (int r = 0; r < 4; ++r) acc[nt][r] = 0.f;
    float gdot = 0.f;
    if (tid < 64) {                          // stage the 2 x-rows (fp32)
        int bb = tid >> 5, p = tid & 31;
        f32x4 xa = *(const f32x4*)(x + (size_t)(b0 + bb) * E_DIM + p * 8);
        f32x4 xb = *(const f32x4*)(x + (size_t)(b0 + bb) * E_DIM + p * 8 + 4);
        *(f32x4*)(&sXf[bb][p * 8]) = xa;
        *(f32x4*)(&sXf[bb][p * 8 + 4]) = xb;
    }
    int arow = tid >> 2, akk = (tid & 3) * 8;
    const float* astage = state + (size_t)(m0 + arow) * E_DIM + akk;

    // prologue: load tile 0 into regs, write to LDS, one barrier
    f32x4 pa0 = *(const f32x4*)(astage);
    f32x4 pa1 = *(const f32x4*)(astage + 4);
    bf16x8 pb0, pb1, pb2, pb3;
    {
        const bf16_t* up = Ubf + (size_t)(tid >> 2) * E_DIM + akk;
        pb0 = *(const bf16x8*)(up);
        pb1 = *(const bf16x8*)(up + 64 * E_DIM);
        pb2 = *(const bf16x8*)(up + 128 * E_DIM);
        pb3 = *(const bf16x8*)(up + 192 * E_DIM);
    }
    {
        *(f32x4*)(&sAf[arow][akk]) = pa0;
        *(f32x4*)(&sAf[arow][akk + 4]) = pa1;
        bf16x8 r;
        r[0] = (bf16_t)pa0[0]; r[1] = (bf16_t)pa0[1]; r[2] = (bf16_t)pa0[2]; r[3] = (bf16_t)pa0[3];
        r[4] = (bf16_t)pa1[0]; r[5] = (bf16_t)pa1[1]; r[6] = (bf16_t)pa1[2]; r[7] = (bf16_t)pa1[3];
        *(bf16x8*)(&sA[arow][akk]) = r;
        *(bf16x8*)(&sB[arow][akk]) = pb0;
        *(bf16x8*)(&sB[64 + arow][akk]) = pb1;
        *(bf16x8*)(&sB[128 + arow][akk]) = pb2;
        *(bf16x8*)(&sB[192 + arow][akk]) = pb3;
    }
    __syncthreads();

    for (int kc = 0; kc < 8; ++kc) {
        // issue next-tile global loads (latency hides under MFMA+gdot below)
        if (kc < 7) {
            int k0n = (kc + 1) * BK;
            pa0 = *(const f32x4*)(astage + k0n);
            pa1 = *(const f32x4*)(astage + k0n + 4);
            const bf16_t* up = Ubf + (size_t)(tid >> 2) * E_DIM + k0n + akk;
            pb0 = *(const bf16x8*)(up);
            pb1 = *(const bf16x8*)(up + 64 * E_DIM);
            pb2 = *(const bf16x8*)(up + 128 * E_DIM);
            pb3 = *(const bf16x8*)(up + 192 * E_DIM);
        }
        int k0 = kc * BK;
        // compute on LDS tile kc
        bf16x8 af = *(const bf16x8*)(&sA[w * 16 + l15][quad * 8]);
#pragma unroll
        for (int i = 0; i < 8; ++i)
            gdot += sAf[w * 16 + l15][quad * 8 + i] * sXf[w >> 1][k0 + quad * 8 + i];
#pragma unroll
        for (int nt = 0; nt < 16; ++nt) {
            bf16x8 bfr = *(const bf16x8*)(&sB[nt * 16 + l15][quad * 8]);
            acc[nt] = __builtin_amdgcn_mfma_f32_16x16x32_bf16(af, bfr, acc[nt], 0, 0, 0);
        }
        __syncthreads();                     // all waves done reading tile kc
        if (kc < 7) {                        // write-late: regs -> LDS
            *(f32x4*)(&sAf[arow][akk]) = pa0;
            *(f32x4*)(&sAf[arow][akk + 4]) = pa1;
            bf16x8 r;
            r[0] = (bf16_t)pa0[0]; r[1] = (bf16_t)pa0[1]; r[2] = (bf16_t)pa0[2]; r[3] = (bf16_t)pa0[3];
            r[4] = (bf16_t)pa1[0]; r[5] = (bf16_t)pa1[1]; r[6] = (bf16_t)pa1[2]; r[7] = (bf16_t)pa1[3];
            *(bf16x8*)(&sA[arow][akk]) = r;
            *(bf16x8*)(&sB[arow][akk]) = pb0;
            *(bf16x8*)(&sB[64 + arow][akk]) = pb1;
            *(bf16x8*)(&sB[128 + arow][akk]) = pb2;
            *(bf16x8*)(&sB[192 + arow][akk]) = pb3;
        }
        __syncthreads();                     // tile kc+1 visible
    }
    // reduce gate dot across quads (k was split quad-wise): lanes sharing l15
    gdot += __shfl_xor(gdot, 16);
    gdot += __shfl_xor(gdot, 32);
    int bw = b0 + (w >> 1);                 // one b per wave
    float garg = gdot + xk[(size_t)bw * J_DIM + (w & 1) * 16 + l15];
    float gv = 1.f / (1.f + expf(-garg));
    float gate[4];
#pragma unroll
    for (int r = 0; r < 4; ++r) gate[r] = __shfl(gv, quad * 4 + r);
    // epilogue: C/D layout row = quad*4+r, col = nt*16+l15
    float sumsq[4] = {0.f, 0.f, 0.f, 0.f};
    const float* wxrow = wx + (size_t)bw * E_DIM;
#pragma unroll
    for (int nt = 0; nt < 16; ++nt) {
        int f = nt * 16 + l15;
        float wxf = wxrow[f];
#pragma unroll
        for (int r = 0; r < 4; ++r) {
            int rl = quad * 4 + r;
            int jidx = (w & 1) * 16 + rl;
            float c = acc[nt][r] + wxf + vkb[(size_t)jidx * E_DIM + f];
            c = fmaxf(c, 0.f);
            float sv = state[(size_t)(m0 + w * 16 + rl) * E_DIM + f]; // L2-hot re-read
            float t = fmaf(gate[r], c, sv);
            acc[nt][r] = t;
            sumsq[r] += t * t;
        }
    }
    float rn[4];
#pragma unroll
    for (int r = 0; r < 4; ++r) {
        float s2 = sumsq[r];
        s2 += __shfl_xor(s2, 1);
        s2 += __shfl_xor(s2, 2);
        s2 += __shfl_xor(s2, 4);
        s2 += __shfl_xor(s2, 8);
        rn[r] = 1.f / (sqrtf(s2) + 1e-8f);
    }
#pragma unroll
    for (int nt = 0; nt < 16; ++nt)
#pragma unroll
        for (int r = 0; r < 4; ++r)
            out[(size_t)(m0 + w * 16 + quad * 4 + r) * E_DIM + nt * 16 + l15] =
                acc[nt][r] * rn[r];
}

extern "C" void kernel_launch(void* const* d_in, const int* in_sizes, int n_in,
                              void* d_out, int out_size, void* d_ws, size_t ws_size,
                              hipStream_t stream) {
    const float* x     = (const float*)d_in[0];
    const float* state = (const float*)d_in[1];
    const float* keys  = (const float*)d_in[2];
    const float* U     = (const float*)d_in[3];
    const float* V     = (const float*)d_in[4];
    const float* W     = (const float*)d_in[5];
    const float* bias  = (const float*)d_in[6];
    float* out = (float*)d_out;

    float* wsf = (float*)d_ws;
    float* wx  = wsf;                                   // 4096*256 fp32 = 4 MB
    float* xk  = wsf + (size_t)B_DIM * E_DIM;           // 4096*32  fp32 = 512 KB
    float* vkb = xk + (size_t)B_DIM * J_DIM;            // 32*256   fp32 = 32 KB
    bf16_t* Ubf = (bf16_t*)(vkb + (size_t)J_DIM * E_DIM); // 256*256 bf16 = 128 KB

    xkvkb_kernel<<<608, 256, 0, stream>>>(x, keys, U, V, bias, xk, vkb, Ubf);
    wx_kernel<<<256, 256, 0, stream>>>(x, W, wx);
    memcell_kernel<<<M_DIM / BM, 256, 0, stream>>>(x, state, Ubf, wx, xk, vkb, out);
}